// Round 5
// baseline (1473.726 us; speedup 1.0000x reference)
//
#include <hip/hip_runtime.h>

typedef __bf16 bf16x8 __attribute__((ext_vector_type(8)));
typedef float  f32x4  __attribute__((ext_vector_type(4)));

#define MFMA16(a,b,c) __builtin_amdgcn_mfma_f32_16x16x32_bf16((a),(b),(c),0,0,0)

constexpr int  HID  = 768;
constexpr long T    = 16384;          // NUM_SEQS * SEQ_LEN
constexpr long SZ   = T * HID;        // 12,582,912 elements
constexpr int  SEQ  = 2048;
constexpr int  NH   = 12;
constexpr int  HD   = 64;
constexpr int  WELE = HID * HID;      // 589,824

// Q pre-scale: (1/sqrt(64)) * log2(e)  -> softmax done in exp2 domain
constexpr float QSCALE = 0.125f * 1.4426950408889634f;
// log2(10000)/32 for RoPE inv_freq = 2^(-d * L10K32)
constexpr float L10K32 = 13.287712379549449f / 32.0f;

// ---------------------------------------------------------------------------
// Weight convert+transpose, LDS-tiled. Wt[n][k] = bf16(W[k][n]).
// ---------------------------------------------------------------------------
__global__ __launch_bounds__(256)
void wconv_kernel(const float* __restrict__ W0, __bf16* __restrict__ T0,
                  const float* __restrict__ W1, __bf16* __restrict__ T1,
                  const float* __restrict__ W2, __bf16* __restrict__ T2,
                  const float* __restrict__ W3, __bf16* __restrict__ T3) {
    const float* W; __bf16* Wt;
    switch (blockIdx.z) {
        case 0: W = W0; Wt = T0; break;
        case 1: W = W1; Wt = T1; break;
        case 2: W = W2; Wt = T2; break;
        default: W = W3; Wt = T3; break;
    }
    __shared__ float tile[64][65];
    int n0 = blockIdx.x * 64, k0 = blockIdx.y * 64;
    int c = threadIdx.x & 63, rr = threadIdx.x >> 6;
#pragma unroll
    for (int i = 0; i < 16; i++) {
        int r = i * 4 + rr;
        tile[r][c] = W[(long)(k0 + r) * HID + n0 + c];
    }
    __syncthreads();
#pragma unroll
    for (int i = 0; i < 16; i++) {
        int r = i * 4 + rr;
        Wt[(long)(n0 + r) * HID + k0 + c] = (__bf16)tile[c][r];
    }
}

// ---------------------------------------------------------------------------
// LayerNorm: x_bf16[row][:] = LN(hidden[row][:]) * w + b
// ---------------------------------------------------------------------------
__global__ __launch_bounds__(256)
void ln_kernel(const float* __restrict__ hs, const float* __restrict__ w,
               const float* __restrict__ b, __bf16* __restrict__ xbf) {
    int row = blockIdx.x, tid = threadIdx.x;
    const float* hr = hs + (long)row * HID;
    float v0 = hr[tid], v1 = hr[tid + 256], v2 = hr[tid + 512];
    float s  = v0 + v1 + v2;
    float s2 = v0 * v0 + v1 * v1 + v2 * v2;
#pragma unroll
    for (int off = 1; off < 64; off <<= 1) {
        s  += __shfl_xor(s, off);
        s2 += __shfl_xor(s2, off);
    }
    __shared__ float red[8];
    int wave = tid >> 6;
    if ((tid & 63) == 0) { red[wave] = s; red[4 + wave] = s2; }
    __syncthreads();
    s  = red[0] + red[1] + red[2] + red[3];
    s2 = red[4] + red[5] + red[6] + red[7];
    float mu   = s * (1.0f / HID);
    float var  = s2 * (1.0f / HID) - mu * mu;
    float rstd = rsqrtf(var + 1e-12f);
    long base = (long)row * HID;
    xbf[base + tid]       = (__bf16)((v0 - mu) * rstd * w[tid]       + b[tid]);
    xbf[base + tid + 256] = (__bf16)((v1 - mu) * rstd * w[tid + 256] + b[tid + 256]);
    xbf[base + tid + 512] = (__bf16)((v2 - mu) * rstd * w[tid + 512] + b[tid + 512]);
}

// ---------------------------------------------------------------------------
// GEMM fragment set: A-frag + 4 B-frags for one 32-wide k-step
// ---------------------------------------------------------------------------
struct GFrags { bf16x8 af; bf16x8 bf[4]; };

__device__ __forceinline__ void g_load(const __bf16* __restrict__ arow,
                                       const __bf16* __restrict__ brow,
                                       int k0, GFrags& f) {
    f.af = *(const bf16x8*)(arow + k0);
#pragma unroll
    for (int nc = 0; nc < 4; nc++)
        f.bf[nc] = *(const bf16x8*)(brow + nc * 16 * HID + k0);
}

// ---------------------------------------------------------------------------
// GEMM: C[M,N] = A[M,HID] @ Bt[N,HID]^T + bias. 64x64 block, 4 waves x 16 m.
// Ping-pong register prefetch over 24 k-steps (distance-1 software pipeline).
// MODE 3: Q/K proj + fused RoPE (+ scale for Q). grid (T/64, 12).
// MODE 1: V proj A=Wv^T, B=x. grid (12, T/64). out vt[..d..][pos] coalesced.
// MODE 2: final proj fp32 = acc + bias + resid. grid (T/64, 12).
// ---------------------------------------------------------------------------
template <int MODE>
__global__ __launch_bounds__(256)
void gemm_bt(const __bf16* __restrict__ A, const __bf16* __restrict__ Bt,
             const float* __restrict__ bias, __bf16* __restrict__ outb,
             const __bf16* __restrict__ resid, float* __restrict__ outf,
             float scale) {
    int tid = threadIdx.x, wave = tid >> 6, lane = tid & 63;
    int lr = lane & 15, lk = (lane >> 4) * 8, q4 = (lane >> 4) * 4;
    long m0 = (long)blockIdx.x * 64 + wave * 16;
    int  n0 = blockIdx.y * 64;
    f32x4 acc[4] = {{0,0,0,0},{0,0,0,0},{0,0,0,0},{0,0,0,0}};
    const __bf16* arow = A + (m0 + lr) * HID + lk;
    const __bf16* brow = Bt + (long)(n0 + lr) * HID + lk;

    GFrags fA, fB;
    g_load(arow, brow, 0, fA);
    for (int k0 = 0; k0 < HID; k0 += 64) {
        g_load(arow, brow, k0 + 32, fB);
#pragma unroll
        for (int nc = 0; nc < 4; nc++) acc[nc] = MFMA16(fA.af, fA.bf[nc], acc[nc]);
        int nk = k0 + 64; if (nk >= HID) nk = 0;
        g_load(arow, brow, nk, fA);
#pragma unroll
        for (int nc = 0; nc < 4; nc++) acc[nc] = MFMA16(fB.af, fB.bf[nc], acc[nc]);
    }

    if (MODE == 3) {
        float f1 = __builtin_amdgcn_exp2f(-(float)lr * L10K32);
        float f2 = __builtin_amdgcn_exp2f(-(float)(lr + 16) * L10K32);
        float b0 = bias[n0 + lr],      b1 = bias[n0 + 16 + lr];
        float b2 = bias[n0 + 32 + lr], b3 = bias[n0 + 48 + lr];
#pragma unroll
        for (int r = 0; r < 4; r++) {
            long row = m0 + q4 + r;
            int pos = (int)(row & (SEQ - 1));
            float s1, c1, s2, c2;
            __sincosf((float)pos * f1, &s1, &c1);
            __sincosf((float)pos * f2, &s2, &c2);
            float v0 = acc[0][r] + b0, v1 = acc[1][r] + b1;
            float v2 = acc[2][r] + b2, v3 = acc[3][r] + b3;
            __bf16* ob = outb + row * HID + n0;
            ob[lr]      = (__bf16)((v0 * c1 - v2 * s1) * scale);
            ob[16 + lr] = (__bf16)((v1 * c2 - v3 * s2) * scale);
            ob[32 + lr] = (__bf16)((v2 * c1 + v0 * s1) * scale);
            ob[48 + lr] = (__bf16)((v3 * c2 + v1 * s2) * scale);
        }
    } else if (MODE == 1) {
#pragma unroll
        for (int r = 0; r < 4; r++) {
            int d = (int)(m0 + q4 + r);
            float bv = bias[d];
            int hh = d >> 6, dd = d & 63;
#pragma unroll
            for (int nc = 0; nc < 4; nc++) {
                int posg = n0 + nc * 16 + lr;
                int sq = posg >> 11, pos = posg & (SEQ - 1);
                outb[((long)((sq * NH + hh) * HD + dd) << 11) + pos] =
                    (__bf16)(acc[nc][r] + bv);
            }
        }
    } else { // MODE 2
#pragma unroll
        for (int nc = 0; nc < 4; nc++) {
            int col = n0 + nc * 16 + lr;
            float bv = bias[col];
#pragma unroll
            for (int r = 0; r < 4; r++) {
                long row = m0 + q4 + r;
                outf[row * HID + col] = acc[nc][r] + bv + (float)resid[row * HID + col];
            }
        }
    }
}

// ---------------------------------------------------------------------------
// Flash attention with distance-1 register prefetch (ping-pong 64-key tiles).
// Block = 64 q-rows x 1 head x 1 seq; 4 waves each own 16 q-rows + private
// P tile in LDS. Per 64-key tile: 8 QK MFMA -> softmax -> P via LDS -> 8 PV
// MFMA, while the next tile's 16 loads are in flight. No barriers.
// P row stride 68 elems (136B): quad rows hit banks {0,8,16,24} -> u16
// scatter conflict-free; b128 reads 2-way (free).
// ---------------------------------------------------------------------------
__device__ __forceinline__ void a_loadK(const __bf16* __restrict__ kbase,
                                        int kb, int lr, int lk, bf16x8* kf) {
#pragma unroll
    for (int j = 0; j < 4; j++) {
        const __bf16* krow = kbase + (long)(kb + j * 16 + lr) * HID;
        kf[j * 2]     = *(const bf16x8*)(krow + lk);
        kf[j * 2 + 1] = *(const bf16x8*)(krow + 32 + lk);
    }
}
__device__ __forceinline__ void a_loadV(const __bf16* __restrict__ vbase,
                                        int kb, int lr, int lk, bf16x8* vf) {
#pragma unroll
    for (int t = 0; t < 2; t++)
#pragma unroll
        for (int d = 0; d < 4; d++)
            vf[t * 4 + d] = *(const bf16x8*)(vbase + (long)(d * 16 + lr) * SEQ + kb + t * 32 + lk);
}

__global__ __launch_bounds__(256)
void attn_kernel(const __bf16* __restrict__ q, const __bf16* __restrict__ k,
                 const __bf16* __restrict__ vt, __bf16* __restrict__ att) {
    int tid = threadIdx.x, wave = tid >> 6, lane = tid & 63;
    int qt = blockIdx.x, h = blockIdx.y, s = blockIdx.z;
    int lr = lane & 15, lk = (lane >> 4) * 8, q4 = (lane >> 4) * 4;
    long q0 = (long)s * SEQ + qt * 64 + wave * 16;

    const __bf16* qrow = q + (q0 + lr) * HID + h * HD;
    bf16x8 qf0 = *(const bf16x8*)(qrow + lk);
    bf16x8 qf1 = *(const bf16x8*)(qrow + 32 + lk);

    const f32x4 vzero = {0.f, 0.f, 0.f, 0.f};
    f32x4 o[4] = {vzero, vzero, vzero, vzero};
    float m_i[4]  = {-INFINITY, -INFINITY, -INFINITY, -INFINITY};
    float lsum[4] = {0.f, 0.f, 0.f, 0.f};

    __shared__ __align__(16) __bf16 plds[4][16][68];

    const __bf16* kbase = k + (long)s * SEQ * HID + h * HD;
    const __bf16* vbase = vt + ((long)(s * NH + h) * HD) * SEQ;

    bf16x8 kA[8], vA[8], kB[8], vB[8];
    a_loadK(kbase, 0, lr, lk, kA);
    a_loadV(vbase, 0, lr, lk, vA);

    for (int kb = 0; kb < SEQ; kb += 128) {
        // prefetch tile (kb+64) while computing tile kb
        a_loadK(kbase, kb + 64, lr, lk, kB);
        a_loadV(vbase, kb + 64, lr, lk, vB);
        {
            f32x4 st[4];
#pragma unroll
            for (int j = 0; j < 4; j++) {
                f32x4 sj = MFMA16(qf0, kA[j * 2], vzero);
                st[j] = MFMA16(qf1, kA[j * 2 + 1], sj);
            }
            float alpha[4];
#pragma unroll
            for (int r = 0; r < 4; r++) {
                float mx = fmaxf(fmaxf(st[0][r], st[1][r]), fmaxf(st[2][r], st[3][r]));
#pragma unroll
                for (int off = 1; off < 16; off <<= 1) mx = fmaxf(mx, __shfl_xor(mx, off));
                float nm = fmaxf(m_i[r], mx);
                alpha[r] = __builtin_amdgcn_exp2f(m_i[r] - nm);
                m_i[r] = nm;
                float rs = 0.f;
#pragma unroll
                for (int j = 0; j < 4; j++) {
                    float e = __builtin_amdgcn_exp2f(st[j][r] - nm);
                    rs += e;
                    plds[wave][q4 + r][j * 16 + lr] = (__bf16)e;
                }
                lsum[r] = lsum[r] * alpha[r] + rs;
            }
#pragma unroll
            for (int r = 0; r < 4; r++) {
                o[0][r] *= alpha[r]; o[1][r] *= alpha[r];
                o[2][r] *= alpha[r]; o[3][r] *= alpha[r];
            }
#pragma unroll
            for (int t = 0; t < 2; t++) {
                bf16x8 pa = *(const bf16x8*)&plds[wave][lr][t * 32 + lk];
#pragma unroll
                for (int d = 0; d < 4; d++) o[d] = MFMA16(pa, vA[t * 4 + d], o[d]);
            }
        }
        // prefetch tile (kb+128, or wrap) while computing tile kb+64
        int nxt = (kb + 128 < SEQ) ? kb + 128 : 0;
        a_loadK(kbase, nxt, lr, lk, kA);
        a_loadV(vbase, nxt, lr, lk, vA);
        {
            f32x4 st[4];
#pragma unroll
            for (int j = 0; j < 4; j++) {
                f32x4 sj = MFMA16(qf0, kB[j * 2], vzero);
                st[j] = MFMA16(qf1, kB[j * 2 + 1], sj);
            }
            float alpha[4];
#pragma unroll
            for (int r = 0; r < 4; r++) {
                float mx = fmaxf(fmaxf(st[0][r], st[1][r]), fmaxf(st[2][r], st[3][r]));
#pragma unroll
                for (int off = 1; off < 16; off <<= 1) mx = fmaxf(mx, __shfl_xor(mx, off));
                float nm = fmaxf(m_i[r], mx);
                alpha[r] = __builtin_amdgcn_exp2f(m_i[r] - nm);
                m_i[r] = nm;
                float rs = 0.f;
#pragma unroll
                for (int j = 0; j < 4; j++) {
                    float e = __builtin_amdgcn_exp2f(st[j][r] - nm);
                    rs += e;
                    plds[wave][q4 + r][j * 16 + lr] = (__bf16)e;
                }
                lsum[r] = lsum[r] * alpha[r] + rs;
            }
#pragma unroll
            for (int r = 0; r < 4; r++) {
                o[0][r] *= alpha[r]; o[1][r] *= alpha[r];
                o[2][r] *= alpha[r]; o[3][r] *= alpha[r];
            }
#pragma unroll
            for (int t = 0; t < 2; t++) {
                bf16x8 pa = *(const bf16x8*)&plds[wave][lr][t * 32 + lk];
#pragma unroll
                for (int d = 0; d < 4; d++) o[d] = MFMA16(pa, vB[t * 4 + d], o[d]);
            }
        }
    }

#pragma unroll
    for (int r = 0; r < 4; r++) {
        float l = lsum[r];
#pragma unroll
        for (int off = 1; off < 16; off <<= 1) l += __shfl_xor(l, off);
        float inv = 1.0f / l;
        long row = q0 + q4 + r;
        __bf16* ob = att + row * HID + h * HD;
        ob[0 * 16 + lr] = (__bf16)(o[0][r] * inv);
        ob[1 * 16 + lr] = (__bf16)(o[1][r] * inv);
        ob[2 * 16 + lr] = (__bf16)(o[2][r] * inv);
        ob[3 * 16 + lr] = (__bf16)(o[3][r] * inv);
    }
}

// ---------------------------------------------------------------------------
extern "C" void kernel_launch(void* const* d_in, const int* in_sizes, int n_in,
                              void* d_out, int out_size, void* d_ws, size_t ws_size,
                              hipStream_t stream) {
    const float* hs    = (const float*)d_in[0];
    const float* normw = (const float*)d_in[3];
    const float* normb = (const float*)d_in[4];
    const float* Wq = (const float*)d_in[5];
    const float* bq = (const float*)d_in[6];
    const float* Wk = (const float*)d_in[7];
    const float* bk = (const float*)d_in[8];
    const float* Wv = (const float*)d_in[9];
    const float* bv = (const float*)d_in[10];
    const float* Wo = (const float*)d_in[11];
    const float* bo = (const float*)d_in[12];

    __bf16* base = (__bf16*)d_ws;
    __bf16* x   = base;            // SZ
    __bf16* qb  = base + SZ;       // SZ
    __bf16* kb  = base + 2 * SZ;   // SZ
    __bf16* vtb = base + 3 * SZ;   // SZ  ([s][h][d][pos])
    __bf16* att = base + 4 * SZ;   // SZ
    __bf16* wqt = base + 5 * SZ;
    __bf16* wkt = wqt + WELE;
    __bf16* wvt = wkt + WELE;
    __bf16* wot = wvt + WELE;

    wconv_kernel<<<dim3(12, 12, 4), 256, 0, stream>>>(Wq, wqt, Wk, wkt, Wv, wvt, Wo, wot);

    ln_kernel<<<(int)T, 256, 0, stream>>>(hs, normw, normb, x);

    gemm_bt<3><<<dim3(T / 64, HID / 64), 256, 0, stream>>>(x, wqt, bq, qb, nullptr, nullptr, QSCALE);
    gemm_bt<3><<<dim3(T / 64, HID / 64), 256, 0, stream>>>(x, wkt, bk, kb, nullptr, nullptr, 1.0f);
    gemm_bt<1><<<dim3(HID / 64, T / 64), 256, 0, stream>>>(wvt, x, bv, vtb, nullptr, nullptr, 1.0f);

    attn_kernel<<<dim3(SEQ / 64, NH, 8), 256, 0, stream>>>(qb, kb, vtb, att);

    gemm_bt<2><<<dim3(T / 64, HID / 64), 256, 0, stream>>>(att, wot, bo, nullptr, x, (float*)d_out, 1.0f);
}

// Round 6
// 928.174 us; speedup vs baseline: 1.5878x; 1.5878x over previous
//
#include <hip/hip_runtime.h>

typedef __bf16 bf16x8 __attribute__((ext_vector_type(8)));
typedef float  f32x4  __attribute__((ext_vector_type(4)));

#define MFMA16(a,b,c) __builtin_amdgcn_mfma_f32_16x16x32_bf16((a),(b),(c),0,0,0)

constexpr int  HID  = 768;
constexpr long T    = 16384;          // NUM_SEQS * SEQ_LEN
constexpr long SZ   = T * HID;        // 12,582,912 elements
constexpr int  SEQ  = 2048;
constexpr int  NH   = 12;
constexpr int  HD   = 64;
constexpr int  WELE = HID * HID;      // 589,824

// Q pre-scale: (1/sqrt(64)) * log2(e)  -> softmax done in exp2 domain
constexpr float QSCALE = 0.125f * 1.4426950408889634f;
// log2(10000)/32 for RoPE inv_freq = 2^(-d * L10K32)
constexpr float L10K32 = 13.287712379549449f / 32.0f;

__device__ __forceinline__ unsigned pkbf(float a, float b) {
    union { __bf16 h[2]; unsigned u; } x;
    x.h[0] = (__bf16)a; x.h[1] = (__bf16)b; return x.u;
}

// ---------------------------------------------------------------------------
// Weight convert+transpose, LDS-tiled. Wt[n][k] = bf16(W[k][n]).
// ---------------------------------------------------------------------------
__global__ __launch_bounds__(256)
void wconv_kernel(const float* __restrict__ W0, __bf16* __restrict__ T0,
                  const float* __restrict__ W1, __bf16* __restrict__ T1,
                  const float* __restrict__ W2, __bf16* __restrict__ T2,
                  const float* __restrict__ W3, __bf16* __restrict__ T3) {
    const float* W; __bf16* Wt;
    switch (blockIdx.z) {
        case 0: W = W0; Wt = T0; break;
        case 1: W = W1; Wt = T1; break;
        case 2: W = W2; Wt = T2; break;
        default: W = W3; Wt = T3; break;
    }
    __shared__ float tile[64][65];
    int n0 = blockIdx.x * 64, k0 = blockIdx.y * 64;
    int c = threadIdx.x & 63, rr = threadIdx.x >> 6;
#pragma unroll
    for (int i = 0; i < 16; i++) {
        int r = i * 4 + rr;
        tile[r][c] = W[(long)(k0 + r) * HID + n0 + c];
    }
    __syncthreads();
#pragma unroll
    for (int i = 0; i < 16; i++) {
        int r = i * 4 + rr;
        Wt[(long)(n0 + r) * HID + k0 + c] = (__bf16)tile[c][r];
    }
}

// ---------------------------------------------------------------------------
// LayerNorm
// ---------------------------------------------------------------------------
__global__ __launch_bounds__(256)
void ln_kernel(const float* __restrict__ hs, const float* __restrict__ w,
               const float* __restrict__ b, __bf16* __restrict__ xbf) {
    int row = blockIdx.x, tid = threadIdx.x;
    const float* hr = hs + (long)row * HID;
    float v0 = hr[tid], v1 = hr[tid + 256], v2 = hr[tid + 512];
    float s  = v0 + v1 + v2;
    float s2 = v0 * v0 + v1 * v1 + v2 * v2;
#pragma unroll
    for (int off = 1; off < 64; off <<= 1) {
        s  += __shfl_xor(s, off);
        s2 += __shfl_xor(s2, off);
    }
    __shared__ float red[8];
    int wave = tid >> 6;
    if ((tid & 63) == 0) { red[wave] = s; red[4 + wave] = s2; }
    __syncthreads();
    s  = red[0] + red[1] + red[2] + red[3];
    s2 = red[4] + red[5] + red[6] + red[7];
    float mu   = s * (1.0f / HID);
    float var  = s2 * (1.0f / HID) - mu * mu;
    float rstd = rsqrtf(var + 1e-12f);
    long base = (long)row * HID;
    xbf[base + tid]       = (__bf16)((v0 - mu) * rstd * w[tid]       + b[tid]);
    xbf[base + tid + 256] = (__bf16)((v1 - mu) * rstd * w[tid + 256] + b[tid + 256]);
    xbf[base + tid + 512] = (__bf16)((v2 - mu) * rstd * w[tid + 512] + b[tid + 512]);
}

// ---------------------------------------------------------------------------
// GEMM: C[M,N] = A[M,HID] @ Bt[N,HID]^T + bias.  128x64 block, 4 waves,
// each wave 32 m-rows (two 16-row subtiles) x 64 n: 8 MFMA per 6 loads.
// MODE 3: Q/K proj + fused RoPE (+ scale for Q). grid (T/128, 12).
// MODE 1: V proj A=Wv^T (M=768), B=x (N=T). grid (6, T/64); vt out coalesced.
// MODE 2: final proj fp32 = acc + bias + resid. grid (T/128, 12).
// ---------------------------------------------------------------------------
template <int MODE>
__global__ __launch_bounds__(256)
void gemm_bt(const __bf16* __restrict__ A, const __bf16* __restrict__ Bt,
             const float* __restrict__ bias, __bf16* __restrict__ outb,
             const __bf16* __restrict__ resid, float* __restrict__ outf,
             float scale) {
    int tid = threadIdx.x, wave = tid >> 6, lane = tid & 63;
    int lr = lane & 15, lk = (lane >> 4) * 8, q4 = (lane >> 4) * 4;
    long m0 = (long)blockIdx.x * 128 + wave * 32;
    int  n0 = blockIdx.y * 64;
    const f32x4 vzero = {0.f, 0.f, 0.f, 0.f};
    f32x4 acc[2][4];
#pragma unroll
    for (int mm = 0; mm < 2; mm++)
#pragma unroll
        for (int nc = 0; nc < 4; nc++) acc[mm][nc] = vzero;

    const __bf16* ar0 = A + (m0 + lr) * HID + lk;
    const __bf16* ar1 = A + (m0 + 16 + lr) * HID + lk;
    const __bf16* brow = Bt + (long)(n0 + lr) * HID + lk;
    for (int k0 = 0; k0 < HID; k0 += 32) {
        bf16x8 a0 = *(const bf16x8*)(ar0 + k0);
        bf16x8 a1 = *(const bf16x8*)(ar1 + k0);
#pragma unroll
        for (int nc = 0; nc < 4; nc++) {
            bf16x8 bfr = *(const bf16x8*)(brow + (long)nc * 16 * HID + k0);
            acc[0][nc] = MFMA16(a0, bfr, acc[0][nc]);
            acc[1][nc] = MFMA16(a1, bfr, acc[1][nc]);
        }
    }

    if (MODE == 3) {
        float f1 = __builtin_amdgcn_exp2f(-(float)lr * L10K32);
        float f2 = __builtin_amdgcn_exp2f(-(float)(lr + 16) * L10K32);
        float b0 = bias[n0 + lr],      b1 = bias[n0 + 16 + lr];
        float b2 = bias[n0 + 32 + lr], b3 = bias[n0 + 48 + lr];
#pragma unroll
        for (int mm = 0; mm < 2; mm++)
#pragma unroll
        for (int r = 0; r < 4; r++) {
            long row = m0 + mm * 16 + q4 + r;
            int pos = (int)(row & (SEQ - 1));
            float s1, c1, s2, c2;
            __sincosf((float)pos * f1, &s1, &c1);
            __sincosf((float)pos * f2, &s2, &c2);
            float v0 = acc[mm][0][r] + b0, v1 = acc[mm][1][r] + b1;
            float v2 = acc[mm][2][r] + b2, v3 = acc[mm][3][r] + b3;
            __bf16* ob = outb + row * HID + n0;
            ob[lr]      = (__bf16)((v0 * c1 - v2 * s1) * scale);
            ob[16 + lr] = (__bf16)((v1 * c2 - v3 * s2) * scale);
            ob[32 + lr] = (__bf16)((v2 * c1 + v0 * s1) * scale);
            ob[48 + lr] = (__bf16)((v3 * c2 + v1 * s2) * scale);
        }
    } else if (MODE == 1) {
#pragma unroll
        for (int mm = 0; mm < 2; mm++)
#pragma unroll
        for (int r = 0; r < 4; r++) {
            int d = (int)(m0 + mm * 16 + q4 + r);
            float bv = bias[d];
            int hh = d >> 6, dd = d & 63;
#pragma unroll
            for (int nc = 0; nc < 4; nc++) {
                int posg = n0 + nc * 16 + lr;
                int sq = posg >> 11, pos = posg & (SEQ - 1);
                outb[((long)((sq * NH + hh) * HD + dd) << 11) + pos] =
                    (__bf16)(acc[mm][nc][r] + bv);
            }
        }
    } else { // MODE 2
#pragma unroll
        for (int nc = 0; nc < 4; nc++) {
            int col = n0 + nc * 16 + lr;
            float bv = bias[col];
#pragma unroll
            for (int mm = 0; mm < 2; mm++)
#pragma unroll
            for (int r = 0; r < 4; r++) {
                long row = m0 + mm * 16 + q4 + r;
                outf[row * HID + col] = acc[mm][nc][r] + bv + (float)resid[row * HID + col];
            }
        }
    }
}

// ---------------------------------------------------------------------------
// Flash attention, TRANSPOSED scores: S^T = K @ Q^T  (A=K, B=Q).
// C-layout: q = lane&15, key = quad*4+reg  ->  softmax reduction is only
// shfl_xor(16)+shfl_xor(32); m/l/alpha are one scalar per lane per subtile;
// P^T keys are register-consecutive -> packed b64 LDS writes (16/tile).
// PV: o^T = V^T @ P^T (A=V^T from vt[d][pos], B=P^T from LDS).
// Wave owns 32 q-rows (2 subtiles); block = 128 q; no barriers (per-wave P).
// ---------------------------------------------------------------------------
__global__ __launch_bounds__(256)
void attn_kernel(const __bf16* __restrict__ q, const __bf16* __restrict__ k,
                 const __bf16* __restrict__ vt, __bf16* __restrict__ att) {
    int tid = threadIdx.x, wave = tid >> 6, lane = tid & 63;
    int lr = lane & 15, quad = lane >> 4;
    int qt = blockIdx.x, h = blockIdx.y, s = blockIdx.z;
    long q0 = (long)s * SEQ + qt * 128 + wave * 32;

    const f32x4 vzero = {0.f, 0.f, 0.f, 0.f};
    // Q B-frags: B[n=lr][kk=quad*8+j], two d-halves, two q-subtiles
    bf16x8 qf[2][2];
#pragma unroll
    for (int m = 0; m < 2; m++) {
        const __bf16* qrow = q + (q0 + m * 16 + lr) * HID + h * HD + quad * 8;
        qf[m][0] = *(const bf16x8*)(qrow);
        qf[m][1] = *(const bf16x8*)(qrow + 32);
    }

    f32x4 o[2][4];
#pragma unroll
    for (int m = 0; m < 2; m++)
#pragma unroll
        for (int d = 0; d < 4; d++) o[m][d] = vzero;
    float m_i[2]  = {-INFINITY, -INFINITY};
    float lsum[2] = {0.f, 0.f};

    // P^T per wave: [32 q-rows][128 keys + 8 pad] (272B rows, 16B-aligned)
    __shared__ __align__(16) __bf16 plds[4][32][136];

    const __bf16* kbase = k + (long)s * SEQ * HID + h * HD + quad * 8;
    const __bf16* vbase = vt + ((long)(s * NH + h) * HD) * SEQ;

    for (int kb = 0; kb < SEQ; kb += 128) {
        // ---- S^T: 8 key-tiles of 16, K-frags shared by both q-subtiles ----
        f32x4 st[2][8];
#pragma unroll
        for (int jt = 0; jt < 8; jt++) {
            const __bf16* krow = kbase + (long)(kb + jt * 16 + lr) * HID;
            bf16x8 kf0 = *(const bf16x8*)(krow);
            bf16x8 kf1 = *(const bf16x8*)(krow + 32);
#pragma unroll
            for (int m = 0; m < 2; m++) {
                f32x4 t0 = MFMA16(kf0, qf[m][0], vzero);
                st[m][jt] = MFMA16(kf1, qf[m][1], t0);
            }
        }
        // ---- online softmax (exp2 domain), per q-subtile ----
        float alpha[2];
#pragma unroll
        for (int m = 0; m < 2; m++) {
            f32x4 mx4 = st[m][0];
#pragma unroll
            for (int jt = 1; jt < 8; jt++) {
                mx4[0] = fmaxf(mx4[0], st[m][jt][0]);
                mx4[1] = fmaxf(mx4[1], st[m][jt][1]);
                mx4[2] = fmaxf(mx4[2], st[m][jt][2]);
                mx4[3] = fmaxf(mx4[3], st[m][jt][3]);
            }
            float mx = fmaxf(fmaxf(mx4[0], mx4[1]), fmaxf(mx4[2], mx4[3]));
            mx = fmaxf(mx, __shfl_xor(mx, 16));
            mx = fmaxf(mx, __shfl_xor(mx, 32));
            float nm = fmaxf(m_i[m], mx);
            alpha[m] = __builtin_amdgcn_exp2f(m_i[m] - nm);
            m_i[m] = nm;
            float rs = 0.f;
#pragma unroll
            for (int jt = 0; jt < 8; jt++) {
                float e0 = __builtin_amdgcn_exp2f(st[m][jt][0] - nm);
                float e1 = __builtin_amdgcn_exp2f(st[m][jt][1] - nm);
                float e2 = __builtin_amdgcn_exp2f(st[m][jt][2] - nm);
                float e3 = __builtin_amdgcn_exp2f(st[m][jt][3] - nm);
                rs += (e0 + e1) + (e2 + e3);
                unsigned long long pw =
                    ((unsigned long long)pkbf(e2, e3) << 32) | pkbf(e0, e1);
                *(unsigned long long*)&plds[wave][m * 16 + lr][jt * 16 + quad * 4] = pw;
            }
            lsum[m] = lsum[m] * alpha[m] + rs;
#pragma unroll
            for (int d = 0; d < 4; d++) o[m][d] *= alpha[m];
        }
        // wave-private LDS: writes -> reads within the same wave only
        asm volatile("s_waitcnt lgkmcnt(0)" ::: "memory");
        // ---- PV: o^T += V^T @ P^T, 4 key-groups of 32 ----
#pragma unroll
        for (int g = 0; g < 4; g++) {
            bf16x8 vf[4];
#pragma unroll
            for (int d = 0; d < 4; d++)
                vf[d] = *(const bf16x8*)(vbase + (long)(d * 16 + lr) * SEQ + kb + g * 32 + quad * 8);
#pragma unroll
            for (int m = 0; m < 2; m++) {
                bf16x8 pb = *(const bf16x8*)&plds[wave][m * 16 + lr][g * 32 + quad * 8];
#pragma unroll
                for (int d = 0; d < 4; d++) o[m][d] = MFMA16(vf[d], pb, o[m][d]);
            }
        }
    }

    // ---- epilogue: l reduce (2 shuffles), normalize, packed b32 stores ----
#pragma unroll
    for (int m = 0; m < 2; m++) {
        float l = lsum[m];
        l += __shfl_xor(l, 16);
        l += __shfl_xor(l, 32);
        float inv = 1.0f / l;
        long row = q0 + m * 16 + lr;
        __bf16* ob = att + row * HID + h * HD + quad * 4;
#pragma unroll
        for (int d = 0; d < 4; d++) {
            unsigned p0 = pkbf(o[m][d][0] * inv, o[m][d][1] * inv);
            unsigned p1 = pkbf(o[m][d][2] * inv, o[m][d][3] * inv);
            *(unsigned*)&ob[d * 16]     = p0;
            *(unsigned*)&ob[d * 16 + 2] = p1;
        }
    }
}

// ---------------------------------------------------------------------------
extern "C" void kernel_launch(void* const* d_in, const int* in_sizes, int n_in,
                              void* d_out, int out_size, void* d_ws, size_t ws_size,
                              hipStream_t stream) {
    const float* hs    = (const float*)d_in[0];
    const float* normw = (const float*)d_in[3];
    const float* normb = (const float*)d_in[4];
    const float* Wq = (const float*)d_in[5];
    const float* bq = (const float*)d_in[6];
    const float* Wk = (const float*)d_in[7];
    const float* bk = (const float*)d_in[8];
    const float* Wv = (const float*)d_in[9];
    const float* bv = (const float*)d_in[10];
    const float* Wo = (const float*)d_in[11];
    const float* bo = (const float*)d_in[12];

    __bf16* base = (__bf16*)d_ws;
    __bf16* x   = base;            // SZ
    __bf16* qb  = base + SZ;       // SZ
    __bf16* kb  = base + 2 * SZ;   // SZ
    __bf16* vtb = base + 3 * SZ;   // SZ  ([s][h][d][pos])
    __bf16* att = base + 4 * SZ;   // SZ
    __bf16* wqt = base + 5 * SZ;
    __bf16* wkt = wqt + WELE;
    __bf16* wvt = wkt + WELE;
    __bf16* wot = wvt + WELE;

    wconv_kernel<<<dim3(12, 12, 4), 256, 0, stream>>>(Wq, wqt, Wk, wkt, Wv, wvt, Wo, wot);

    ln_kernel<<<(int)T, 256, 0, stream>>>(hs, normw, normb, x);

    gemm_bt<3><<<dim3(T / 128, HID / 64), 256, 0, stream>>>(x, wqt, bq, qb, nullptr, nullptr, QSCALE);
    gemm_bt<3><<<dim3(T / 128, HID / 64), 256, 0, stream>>>(x, wkt, bk, kb, nullptr, nullptr, 1.0f);
    gemm_bt<1><<<dim3(HID / 128, T / 64), 256, 0, stream>>>(wvt, x, bv, vtb, nullptr, nullptr, 1.0f);

    attn_kernel<<<dim3(SEQ / 128, NH, 8), 256, 0, stream>>>(qb, kb, vtb, att);

    gemm_bt<2><<<dim3(T / 128, HID / 64), 256, 0, stream>>>(att, wot, bo, nullptr, x, (float*)d_out, 1.0f);
}

// Round 7
// 671.191 us; speedup vs baseline: 2.1957x; 1.3829x over previous
//
#include <hip/hip_runtime.h>

typedef __bf16 bf16x8 __attribute__((ext_vector_type(8)));
typedef float  f32x4  __attribute__((ext_vector_type(4)));

#define MFMA16(a,b,c) __builtin_amdgcn_mfma_f32_16x16x32_bf16((a),(b),(c),0,0,0)

constexpr int  HID  = 768;
constexpr long T    = 16384;          // NUM_SEQS * SEQ_LEN
constexpr long SZ   = T * HID;        // 12,582,912 elements
constexpr int  SEQ  = 2048;
constexpr int  NH   = 12;
constexpr int  HD   = 64;
constexpr int  WELE = HID * HID;      // 589,824

// Q pre-scale: (1/sqrt(64)) * log2(e)  -> softmax done in exp2 domain
constexpr float QSCALE = 0.125f * 1.4426950408889634f;
// log2(10000)/32 for RoPE inv_freq = 2^(-d * L10K32)
constexpr float L10K32 = 13.287712379549449f / 32.0f;

__device__ __forceinline__ unsigned pkbf(float a, float b) {
    union { __bf16 h[2]; unsigned u; } x;
    x.h[0] = (__bf16)a; x.h[1] = (__bf16)b; return x.u;
}

// async global->LDS, 16B per lane; LDS dest = uniform base + lane*16
__device__ __forceinline__ void gld16(const __bf16* g, __bf16* l) {
    __builtin_amdgcn_global_load_lds(
        (const __attribute__((address_space(1))) unsigned int*)g,
        (__attribute__((address_space(3))) unsigned int*)l, 16, 0, 0);
}

// ---------------------------------------------------------------------------
// Weight convert+transpose, LDS-tiled. Wt[n][k] = bf16(W[k][n]).
// ---------------------------------------------------------------------------
__global__ __launch_bounds__(256)
void wconv_kernel(const float* __restrict__ W0, __bf16* __restrict__ T0,
                  const float* __restrict__ W1, __bf16* __restrict__ T1,
                  const float* __restrict__ W2, __bf16* __restrict__ T2,
                  const float* __restrict__ W3, __bf16* __restrict__ T3) {
    const float* W; __bf16* Wt;
    switch (blockIdx.z) {
        case 0: W = W0; Wt = T0; break;
        case 1: W = W1; Wt = T1; break;
        case 2: W = W2; Wt = T2; break;
        default: W = W3; Wt = T3; break;
    }
    __shared__ float tile[64][65];
    int n0 = blockIdx.x * 64, k0 = blockIdx.y * 64;
    int c = threadIdx.x & 63, rr = threadIdx.x >> 6;
#pragma unroll
    for (int i = 0; i < 16; i++) {
        int r = i * 4 + rr;
        tile[r][c] = W[(long)(k0 + r) * HID + n0 + c];
    }
    __syncthreads();
#pragma unroll
    for (int i = 0; i < 16; i++) {
        int r = i * 4 + rr;
        Wt[(long)(n0 + r) * HID + k0 + c] = (__bf16)tile[c][r];
    }
}

// ---------------------------------------------------------------------------
// LayerNorm
// ---------------------------------------------------------------------------
__global__ __launch_bounds__(256)
void ln_kernel(const float* __restrict__ hs, const float* __restrict__ w,
               const float* __restrict__ b, __bf16* __restrict__ xbf) {
    int row = blockIdx.x, tid = threadIdx.x;
    const float* hr = hs + (long)row * HID;
    float v0 = hr[tid], v1 = hr[tid + 256], v2 = hr[tid + 512];
    float s  = v0 + v1 + v2;
    float s2 = v0 * v0 + v1 * v1 + v2 * v2;
#pragma unroll
    for (int off = 1; off < 64; off <<= 1) {
        s  += __shfl_xor(s, off);
        s2 += __shfl_xor(s2, off);
    }
    __shared__ float red[8];
    int wave = tid >> 6;
    if ((tid & 63) == 0) { red[wave] = s; red[4 + wave] = s2; }
    __syncthreads();
    s  = red[0] + red[1] + red[2] + red[3];
    s2 = red[4] + red[5] + red[6] + red[7];
    float mu   = s * (1.0f / HID);
    float var  = s2 * (1.0f / HID) - mu * mu;
    float rstd = rsqrtf(var + 1e-12f);
    long base = (long)row * HID;
    xbf[base + tid]       = (__bf16)((v0 - mu) * rstd * w[tid]       + b[tid]);
    xbf[base + tid + 256] = (__bf16)((v1 - mu) * rstd * w[tid + 256] + b[tid + 256]);
    xbf[base + tid + 512] = (__bf16)((v2 - mu) * rstd * w[tid + 512] + b[tid + 512]);
}

// ---------------------------------------------------------------------------
// GEMM, m97-style: C[M,N] = A[M,HID] @ Bt[N,HID]^T + bias.
// 128x128 block tile, 4 waves (2x2), each 64x64 via 4x4 f32x4 acc.
// BK=64, global_load_lds width-16 staging into 8-row/1056B padded segments:
// frag ds_read_b128 banks = 8*(lr>>3)+4*quad -> exactly 2-way (free).
// MODE 3: Q/K proj + fused RoPE (+scale). grid (T/128, 6). 2 heads/block.
// MODE 1: V proj A=Wv^T (M=768 d), B=x (N=T pos). grid (6, T/128).
// MODE 2: final proj fp32 = acc + bias + resid. grid (T/128, 6).
// ---------------------------------------------------------------------------
constexpr int SEGSZ = 528;   // elements per 8-row segment: 1024B data + 32B pad

template <int MODE>
__global__ __launch_bounds__(256)
void gemm_lds(const __bf16* __restrict__ A, const __bf16* __restrict__ Bt,
              const float* __restrict__ bias, __bf16* __restrict__ outb,
              const __bf16* __restrict__ resid, float* __restrict__ outf,
              float scale) {
    int tid = threadIdx.x, wave = tid >> 6, lane = tid & 63;
    int lr = lane & 15, quad = lane >> 4;
    int wm = wave >> 1, wn = wave & 1;
    long m0 = (long)blockIdx.x * 128;
    int  n0 = blockIdx.y * 128;

    __shared__ __align__(16) __bf16 As[16 * SEGSZ];
    __shared__ __align__(16) __bf16 Bs[16 * SEGSZ];

    const f32x4 vzero = {0.f, 0.f, 0.f, 0.f};
    f32x4 acc[4][4];
#pragma unroll
    for (int ms = 0; ms < 4; ms++)
#pragma unroll
        for (int ns = 0; ns < 4; ns++) acc[ms][ns] = vzero;

    // staging: wave stages segments wave*4 .. wave*4+3 of each tile
    // (seg j = 8 rows; lane: row = lane>>3, 16B chunk = lane&7)
    const __bf16* ga = A  + (long)(m0 + wave * 32 + (lane >> 3)) * HID + (lane & 7) * 8;
    const __bf16* gb = Bt + (long)(n0 + wave * 32 + (lane >> 3)) * HID + (lane & 7) * 8;
    __bf16* la = As + wave * 4 * SEGSZ;
    __bf16* lb = Bs + wave * 4 * SEGSZ;

    // per-lane fragment base (row = ...*16 + lr, k-chunk = quad*8)
    int fbase = (lr >> 3) * SEGSZ + (lr & 7) * 64 + quad * 8;

    for (int k0 = 0; k0 < HID; k0 += 64) {
#pragma unroll
        for (int j = 0; j < 4; j++) {
            gld16(ga + (long)j * 8 * HID + k0, la + j * SEGSZ);
            gld16(gb + (long)j * 8 * HID + k0, lb + j * SEGSZ);
        }
        __syncthreads();           // drains vmcnt(0): staging visible
#pragma unroll
        for (int kk = 0; kk < 64; kk += 32) {
            bf16x8 af[4], bfr[4];
#pragma unroll
            for (int ms = 0; ms < 4; ms++)
                af[ms] = *(const bf16x8*)&As[fbase + (wm * 8 + ms * 2) * SEGSZ + kk];
#pragma unroll
            for (int ns = 0; ns < 4; ns++)
                bfr[ns] = *(const bf16x8*)&Bs[fbase + (wn * 8 + ns * 2) * SEGSZ + kk];
#pragma unroll
            for (int ms = 0; ms < 4; ms++)
#pragma unroll
                for (int ns = 0; ns < 4; ns++)
                    acc[ms][ns] = MFMA16(af[ms], bfr[ns], acc[ms][ns]);
        }
        __syncthreads();           // all reads done before restage
    }

    if (MODE == 3) {
        // wave's 64 cols = one head (head = blockIdx.y*2 + wn), d = ns*16+lr
        int hb = n0 + wn * 64;
        float f1 = __builtin_amdgcn_exp2f(-(float)lr * L10K32);
        float f2 = __builtin_amdgcn_exp2f(-(float)(lr + 16) * L10K32);
        float b0 = bias[hb + lr],      b1 = bias[hb + 16 + lr];
        float b2 = bias[hb + 32 + lr], b3 = bias[hb + 48 + lr];
#pragma unroll
        for (int ms = 0; ms < 4; ms++)
#pragma unroll
        for (int r = 0; r < 4; r++) {
            long row = m0 + wm * 64 + ms * 16 + quad * 4 + r;
            int pos = (int)(row & (SEQ - 1));
            float s1, c1, s2, c2;
            __sincosf((float)pos * f1, &s1, &c1);
            __sincosf((float)pos * f2, &s2, &c2);
            float v0 = acc[ms][0][r] + b0, v1 = acc[ms][1][r] + b1;
            float v2 = acc[ms][2][r] + b2, v3 = acc[ms][3][r] + b3;
            __bf16* ob = outb + row * HID + hb;
            ob[lr]      = (__bf16)((v0 * c1 - v2 * s1) * scale);
            ob[16 + lr] = (__bf16)((v1 * c2 - v3 * s2) * scale);
            ob[32 + lr] = (__bf16)((v2 * c1 + v0 * s1) * scale);
            ob[48 + lr] = (__bf16)((v3 * c2 + v1 * s2) * scale);
        }
    } else if (MODE == 1) {
#pragma unroll
        for (int ms = 0; ms < 4; ms++)
#pragma unroll
        for (int r = 0; r < 4; r++) {
            int d = (int)(m0 + wm * 64 + ms * 16 + quad * 4 + r);   // 0..767
            float bv = bias[d];
            int hh = d >> 6, dd = d & 63;
#pragma unroll
            for (int ns = 0; ns < 4; ns++) {
                int posg = n0 + wn * 64 + ns * 16 + lr;
                int sq = posg >> 11, pos = posg & (SEQ - 1);
                outb[((long)((sq * NH + hh) * HD + dd) << 11) + pos] =
                    (__bf16)(acc[ms][ns][r] + bv);
            }
        }
    } else { // MODE 2
#pragma unroll
        for (int ns = 0; ns < 4; ns++) {
            int col = n0 + wn * 64 + ns * 16 + lr;
            float bv = bias[col];
#pragma unroll
            for (int ms = 0; ms < 4; ms++)
#pragma unroll
            for (int r = 0; r < 4; r++) {
                long row = m0 + wm * 64 + ms * 16 + quad * 4 + r;
                outf[row * HID + col] = acc[ms][ns][r] + bv + (float)resid[row * HID + col];
            }
        }
    }
}

// ---------------------------------------------------------------------------
// Flash attention, TRANSPOSED scores: S^T = K @ Q^T  (A=K, B=Q).  Unchanged
// from R6 (424 us): q = lane&15, key = quad*4+reg; softmax reduces with
// shfl_xor(16/32); P^T packed b64 LDS writes; PV: o^T = V^T @ P^T.
// ---------------------------------------------------------------------------
__global__ __launch_bounds__(256)
void attn_kernel(const __bf16* __restrict__ q, const __bf16* __restrict__ k,
                 const __bf16* __restrict__ vt, __bf16* __restrict__ att) {
    int tid = threadIdx.x, wave = tid >> 6, lane = tid & 63;
    int lr = lane & 15, quad = lane >> 4;
    int qt = blockIdx.x, h = blockIdx.y, s = blockIdx.z;
    long q0 = (long)s * SEQ + qt * 128 + wave * 32;

    const f32x4 vzero = {0.f, 0.f, 0.f, 0.f};
    bf16x8 qf[2][2];
#pragma unroll
    for (int m = 0; m < 2; m++) {
        const __bf16* qrow = q + (q0 + m * 16 + lr) * HID + h * HD + quad * 8;
        qf[m][0] = *(const bf16x8*)(qrow);
        qf[m][1] = *(const bf16x8*)(qrow + 32);
    }

    f32x4 o[2][4];
#pragma unroll
    for (int m = 0; m < 2; m++)
#pragma unroll
        for (int d = 0; d < 4; d++) o[m][d] = vzero;
    float m_i[2]  = {-INFINITY, -INFINITY};
    float lsum[2] = {0.f, 0.f};

    __shared__ __align__(16) __bf16 plds[4][32][136];

    const __bf16* kbase = k + (long)s * SEQ * HID + h * HD + quad * 8;
    const __bf16* vbase = vt + ((long)(s * NH + h) * HD) * SEQ;

    for (int kb = 0; kb < SEQ; kb += 128) {
        f32x4 st[2][8];
#pragma unroll
        for (int jt = 0; jt < 8; jt++) {
            const __bf16* krow = kbase + (long)(kb + jt * 16 + lr) * HID;
            bf16x8 kf0 = *(const bf16x8*)(krow);
            bf16x8 kf1 = *(const bf16x8*)(krow + 32);
#pragma unroll
            for (int m = 0; m < 2; m++) {
                f32x4 t0 = MFMA16(kf0, qf[m][0], vzero);
                st[m][jt] = MFMA16(kf1, qf[m][1], t0);
            }
        }
        float alpha[2];
#pragma unroll
        for (int m = 0; m < 2; m++) {
            f32x4 mx4 = st[m][0];
#pragma unroll
            for (int jt = 1; jt < 8; jt++) {
                mx4[0] = fmaxf(mx4[0], st[m][jt][0]);
                mx4[1] = fmaxf(mx4[1], st[m][jt][1]);
                mx4[2] = fmaxf(mx4[2], st[m][jt][2]);
                mx4[3] = fmaxf(mx4[3], st[m][jt][3]);
            }
            float mx = fmaxf(fmaxf(mx4[0], mx4[1]), fmaxf(mx4[2], mx4[3]));
            mx = fmaxf(mx, __shfl_xor(mx, 16));
            mx = fmaxf(mx, __shfl_xor(mx, 32));
            float nm = fmaxf(m_i[m], mx);
            alpha[m] = __builtin_amdgcn_exp2f(m_i[m] - nm);
            m_i[m] = nm;
            float rs = 0.f;
#pragma unroll
            for (int jt = 0; jt < 8; jt++) {
                float e0 = __builtin_amdgcn_exp2f(st[m][jt][0] - nm);
                float e1 = __builtin_amdgcn_exp2f(st[m][jt][1] - nm);
                float e2 = __builtin_amdgcn_exp2f(st[m][jt][2] - nm);
                float e3 = __builtin_amdgcn_exp2f(st[m][jt][3] - nm);
                rs += (e0 + e1) + (e2 + e3);
                unsigned long long pw =
                    ((unsigned long long)pkbf(e2, e3) << 32) | pkbf(e0, e1);
                *(unsigned long long*)&plds[wave][m * 16 + lr][jt * 16 + quad * 4] = pw;
            }
            lsum[m] = lsum[m] * alpha[m] + rs;
#pragma unroll
            for (int d = 0; d < 4; d++) o[m][d] *= alpha[m];
        }
        asm volatile("s_waitcnt lgkmcnt(0)" ::: "memory");
#pragma unroll
        for (int g = 0; g < 4; g++) {
            bf16x8 vf[4];
#pragma unroll
            for (int d = 0; d < 4; d++)
                vf[d] = *(const bf16x8*)(vbase + (long)(d * 16 + lr) * SEQ + kb + g * 32 + quad * 8);
#pragma unroll
            for (int m = 0; m < 2; m++) {
                bf16x8 pb = *(const bf16x8*)&plds[wave][m * 16 + lr][g * 32 + quad * 8];
#pragma unroll
                for (int d = 0; d < 4; d++) o[m][d] = MFMA16(vf[d], pb, o[m][d]);
            }
        }
    }

#pragma unroll
    for (int m = 0; m < 2; m++) {
        float l = lsum[m];
        l += __shfl_xor(l, 16);
        l += __shfl_xor(l, 32);
        float inv = 1.0f / l;
        long row = q0 + m * 16 + lr;
        __bf16* ob = att + row * HID + h * HD + quad * 4;
#pragma unroll
        for (int d = 0; d < 4; d++) {
            unsigned p0 = pkbf(o[m][d][0] * inv, o[m][d][1] * inv);
            unsigned p1 = pkbf(o[m][d][2] * inv, o[m][d][3] * inv);
            *(unsigned*)&ob[d * 16]     = p0;
            *(unsigned*)&ob[d * 16 + 2] = p1;
        }
    }
}

// ---------------------------------------------------------------------------
extern "C" void kernel_launch(void* const* d_in, const int* in_sizes, int n_in,
                              void* d_out, int out_size, void* d_ws, size_t ws_size,
                              hipStream_t stream) {
    const float* hs    = (const float*)d_in[0];
    const float* normw = (const float*)d_in[3];
    const float* normb = (const float*)d_in[4];
    const float* Wq = (const float*)d_in[5];
    const float* bq = (const float*)d_in[6];
    const float* Wk = (const float*)d_in[7];
    const float* bk = (const float*)d_in[8];
    const float* Wv = (const float*)d_in[9];
    const float* bv = (const float*)d_in[10];
    const float* Wo = (const float*)d_in[11];
    const float* bo = (const float*)d_in[12];

    __bf16* base = (__bf16*)d_ws;
    __bf16* x   = base;            // SZ
    __bf16* qb  = base + SZ;       // SZ
    __bf16* kb  = base + 2 * SZ;   // SZ
    __bf16* vtb = base + 3 * SZ;   // SZ  ([s][h][d][pos])
    __bf16* att = base + 4 * SZ;   // SZ
    __bf16* wqt = base + 5 * SZ;
    __bf16* wkt = wqt + WELE;
    __bf16* wvt = wkt + WELE;
    __bf16* wot = wvt + WELE;

    wconv_kernel<<<dim3(12, 12, 4), 256, 0, stream>>>(Wq, wqt, Wk, wkt, Wv, wvt, Wo, wot);

    ln_kernel<<<(int)T, 256, 0, stream>>>(hs, normw, normb, x);

    gemm_lds<3><<<dim3(T / 128, HID / 128), 256, 0, stream>>>(x, wqt, bq, qb, nullptr, nullptr, QSCALE);
    gemm_lds<3><<<dim3(T / 128, HID / 128), 256, 0, stream>>>(x, wkt, bk, kb, nullptr, nullptr, 1.0f);
    gemm_lds<1><<<dim3(HID / 128, T / 128), 256, 0, stream>>>(wvt, x, bv, vtb, nullptr, nullptr, 1.0f);

    attn_kernel<<<dim3(SEQ / 128, NH, 8), 256, 0, stream>>>(qb, kb, vtb, att);

    gemm_lds<2><<<dim3(T / 128, HID / 128), 256, 0, stream>>>(att, wot, bo, nullptr, x, (float*)d_out, 1.0f);
}